// Round 1
// baseline (967.141 us; speedup 1.0000x reference)
//
#include <hip/hip_runtime.h>

#define BB 256
#define NN 512
#define FF 10
#define HH 32

// One block = one (batch, 32-row tile). 16 tiles per batch.
// LDS: s[b] (512x10), k half-tile (256 x pad36), q tile (32 x pad36), weights.
// Total = 20480 + 36864 + 4608 + 2560 = 64512 B -> 2 blocks/CU on 160 KiB LDS.
__global__ __launch_bounds__(256, 2)
void att_kernel(const float* __restrict__ s,
                const float* __restrict__ G,
                const float* __restrict__ Qw,
                const float* __restrict__ Kw,
                float* __restrict__ out) {
    __shared__ float s_lds[NN * FF];        // 20480 B
    __shared__ float k_lds[256 * 36];       // 36864 B (stride 36: 16B-aligned rows)
    __shared__ float q_lds[32 * 36];        // 4608 B
    __shared__ float qw_lds[FF * HH];       // 1280 B
    __shared__ float kw_lds[FF * HH];       // 1280 B

    const int t    = threadIdx.x;
    const int b    = blockIdx.x >> 4;
    const int tile = blockIdx.x & 15;
    const int row0 = tile * 32;
    const int wave = t >> 6;                // 0..3
    const int lane = t & 63;
    const int r0   = wave * 8;              // wave's first local row

    // ---- prefetch this wave's Gmat values (8 rows x 8 chunks) -------------
    // Issued first: 268 MB of HBM reads overlap the whole compute phase.
    float g[8][8];
    const float* Gb = G + (size_t)b * NN * NN;
    #pragma unroll
    for (int r = 0; r < 8; ++r) {
        const float* gp = Gb + (size_t)(row0 + r0 + r) * NN + lane;
        #pragma unroll
        for (int c = 0; c < 8; ++c) g[r][c] = gp[64 * c];
    }

    // ---- stage s[b] and weights into LDS (coalesced) ----------------------
    const float* sb = s + (size_t)b * NN * FF;
    for (int i = t; i < NN * FF; i += 256) s_lds[i] = sb[i];
    for (int i = t; i < FF * HH; i += 256) { qw_lds[i] = Qw[i]; kw_lds[i] = Kw[i]; }
    __syncthreads();

    // ---- q for the block's 32 rows ----------------------------------------
    {
        const int m = t & 31;
        const int rg = t >> 5;              // 0..7
        #pragma unroll
        for (int rr = 0; rr < 4; ++rr) {
            const int rl = rg + 8 * rr;     // 0..31
            float acc = 0.f;
            #pragma unroll
            for (int f = 0; f < FF; ++f)
                acc += s_lds[(row0 + rl) * FF + f] * qw_lds[f * HH + m];
            q_lds[rl * 36 + m] = acc;
        }
    }

    float sc[8][8];
    #pragma unroll
    for (int r = 0; r < 8; ++r)
        #pragma unroll
        for (int c = 0; c < 8; ++c) sc[r][c] = 0.f;

    // ---- two j-half passes: build k half in LDS, accumulate scores --------
    for (int pass = 0; pass < 2; ++pass) {
        const int j0 = pass * 256;
        __syncthreads();   // pass0: q_lds ready gate; pass1: k_lds reuse gate
        {
            const int m = t & 31;
            const int jg = t >> 5;          // 0..7
            for (int i = 0; i < 32; ++i) {
                const int j = jg * 32 + i;  // local 0..255
                float acc = 0.f;
                #pragma unroll
                for (int f = 0; f < FF; ++f)
                    acc += s_lds[(j0 + j) * FF + f] * kw_lds[f * HH + m];
                k_lds[j * 36 + m] = acc;
            }
        }
        __syncthreads();

        #pragma unroll
        for (int mc = 0; mc < 8; ++mc) {
            float4 kf[4];
            #pragma unroll
            for (int c = 0; c < 4; ++c)
                kf[c] = *(const float4*)&k_lds[(lane + 64 * c) * 36 + mc * 4];
            #pragma unroll
            for (int r = 0; r < 8; ++r) {
                const float4 q4 = *(const float4*)&q_lds[(r0 + r) * 36 + mc * 4];
                #pragma unroll
                for (int c = 0; c < 4; ++c) {
                    sc[r][pass * 4 + c] += q4.x * kf[c].x + q4.y * kf[c].y
                                         + q4.z * kf[c].z + q4.w * kf[c].w;
                }
            }
        }
    }

    // ---- epilogue: att = sc^2 * g; row-normalize; store --------------------
    float* ob = out + (size_t)b * NN * NN;
    #pragma unroll
    for (int r = 0; r < 8; ++r) {
        float rs = 0.f;
        #pragma unroll
        for (int c = 0; c < 8; ++c) {
            const float a = sc[r][c] * sc[r][c] * g[r][c];
            sc[r][c] = a;
            rs += a;
        }
        #pragma unroll
        for (int off = 32; off > 0; off >>= 1) rs += __shfl_xor(rs, off, 64);
        const float inv = 1.0f / (rs + 0.001f);
        float* op = ob + (size_t)(row0 + r0 + r) * NN + lane;
        #pragma unroll
        for (int c = 0; c < 8; ++c) op[64 * c] = sc[r][c] * inv;
    }
}

extern "C" void kernel_launch(void* const* d_in, const int* in_sizes, int n_in,
                              void* d_out, int out_size, void* d_ws, size_t ws_size,
                              hipStream_t stream) {
    const float* s  = (const float*)d_in[0];
    const float* G  = (const float*)d_in[1];
    const float* Qw = (const float*)d_in[2];
    const float* Kw = (const float*)d_in[3];
    float* out = (float*)d_out;
    dim3 grid(BB * 16);   // 16 row-tiles per batch
    dim3 block(256);
    att_kernel<<<grid, block, 0, stream>>>(s, G, Qw, Kw, out);
}